// Round 1
// baseline (3036.240 us; speedup 1.0000x reference)
//
#include <hip/hip_runtime.h>
#include <cmath>

// ---------------------------------------------------------------------------
// HeavyEncoderLayer: equivariant message passing layer, fp32.
// N=8000 nodes, E=24000 edges.
// Stage 1: h = CST_SILU*silu(edge_attr @ W1/2) * (1/sqrt(128))      [K1]
// Stage 2: per-edge w = h @ W2 (24000x128x4608 GEMM) fused with the
//          tensor-product contraction -> msg[112], scatter to nm    [K2]
// Stage 3: node gates -> xg[112]                                    [K3]
// Stage 4: masked canonical pooling (atomics)                       [K4]
// Stage 5: quadratic head th[112] per node                          [K5]
// Stage 6: y = mask ? th[canonical] : xg;  out = linear(y)          [K6]
// ---------------------------------------------------------------------------

#define N_NODES 8000
#define N_EDGES 24000

__device__ __constant__ const float INV_SQRT3f = 0.57735026918962576f;
#define PW_MSG0f 0.10206207261596575f   /* sqrt(1/96) */
#define PW1f     0.10206207261596575f   /* PW_MSG1*INV_SQRT3 == sqrt(1/96) */
#define PW_G01f  0.022097086912079608f  /* sqrt(1/2048) */
#define PW_G2f   0.034232659844072866f  /* sqrt(3/2560) */
#define PW_H0f   0.031008683647302115f  /* sqrt(1/1040) */
#define PW_H1f   0.30618621784789724f   /* sqrt(3/32) */
#define RSQRT128f 0.08838834764831845f
#define RSQRT32f  0.17677669529663687f

// ---------------- K1: edge MLP hidden layer ----------------
__global__ __launch_bounds__(256) void k1_h(const float* __restrict__ ea,
                                            const float* __restrict__ W1,
                                            float* __restrict__ h,
                                            float cst_silu) {
  int idx = blockIdx.x * 256 + threadIdx.x;          // e*128 + r, exact grid
  int e = idx >> 7, r = idx & 127;
  float s = 0.5f * (ea[e*4+0]*W1[r] + ea[e*4+1]*W1[128+r] +
                    ea[e*4+2]*W1[256+r] + ea[e*4+3]*W1[384+r]);
  float sg = 1.f / (1.f + expf(-s));
  h[idx] = cst_silu * s * sg * RSQRT128f;            // fold 1/sqrt(128) of W2
}

// ---------------- K2: fused edge GEMM + tensor-product message + scatter ---
// Block: 256 threads = (tx in [0,32), ty in [0,8)). 32 edges per block.
// Per j-chunk (128 cols of W2), thread computes a 4x4 register tile of
// w[e, col] (e = ty*4+i, col = jbase + tx*4 + cc), then folds into msg LDS.
__global__ __launch_bounds__(256) void k2_edge_msg(const float* __restrict__ x,
                                                   const float* __restrict__ ea,
                                                   const float* __restrict__ W2,
                                                   const float* __restrict__ h,
                                                   const int* __restrict__ ei,
                                                   float* __restrict__ nm) {
  __shared__ float xs0_s[32][64];
  __shared__ float xs1_s[32][96];
  __shared__ float a_s[32][4];
  __shared__ float msg_s[32][112];
  __shared__ float hs[32*34];     // [r][e], pad 34 to break bank conflicts
  __shared__ float wsh[32*128];   // staged W2 chunk [r][c]
  __shared__ int srcs_s[32], dsts_s[32];

  const int tid = threadIdx.x;
  const int e0 = blockIdx.x * 32;

  if (tid < 32) { srcs_s[tid] = ei[e0+tid]; dsts_s[tid] = ei[N_EDGES + e0 + tid]; }
  if (tid >= 64 && tid < 192) {
    int t = tid - 64;
    a_s[t>>2][t&3] = ea[(e0 + (t>>2))*4 + (t&3)];
  }
  for (int i = tid; i < 32*112; i += 256) (&msg_s[0][0])[i] = 0.f;
  __syncthreads();
  for (int i = tid; i < 32*160; i += 256) {
    int le = i / 160, f = i - le*160;
    float v = x[srcs_s[le]*160 + f];
    if (f < 64) xs0_s[le][f] = v; else xs1_s[le][f-64] = v;
  }
  __syncthreads();

  const int tx = tid & 31, ty = tid >> 5;

  for (int jc = 0; jc < 36; ++jc) {
    const int jbase = jc * 128;
    float acc[4][4];
#pragma unroll
    for (int i = 0; i < 4; ++i)
#pragma unroll
      for (int cc = 0; cc < 4; ++cc) acc[i][cc] = 0.f;

    for (int rc = 0; rc < 4; ++rc) {
      const int rbase = rc << 5;
      // stage h (transposed): 32 edges x 32 r
      {
        int e = tid >> 3;              // 0..31
        int r4 = (tid & 7) << 2;       // 0..28
        const float4 hv = *(const float4*)&h[(e0+e)*128 + rbase + r4];
        hs[(r4+0)*34 + e] = hv.x;
        hs[(r4+1)*34 + e] = hv.y;
        hs[(r4+2)*34 + e] = hv.z;
        hs[(r4+3)*34 + e] = hv.w;
      }
      // stage W2 chunk: 32 r x 128 c
#pragma unroll
      for (int q = 0; q < 4; ++q) {
        int i2 = tid + q*256;          // 0..1023 float4s
        int r = i2 >> 5;
        int c4 = (i2 & 31) << 2;
        *(float4*)&wsh[r*128 + c4] =
            *(const float4*)&W2[(rbase + r)*4608 + jbase + c4];
      }
      __syncthreads();
#pragma unroll 8
      for (int r = 0; r < 32; ++r) {
        const float4 wv = *(const float4*)&wsh[r*128 + (tx<<2)];
        const float2 ha = *(const float2*)&hs[r*34 + (ty<<2)];
        const float2 hb = *(const float2*)&hs[r*34 + (ty<<2) + 2];
        acc[0][0] += ha.x*wv.x; acc[0][1] += ha.x*wv.y; acc[0][2] += ha.x*wv.z; acc[0][3] += ha.x*wv.w;
        acc[1][0] += ha.y*wv.x; acc[1][1] += ha.y*wv.y; acc[1][2] += ha.y*wv.z; acc[1][3] += ha.y*wv.w;
        acc[2][0] += hb.x*wv.x; acc[2][1] += hb.x*wv.y; acc[2][2] += hb.x*wv.z; acc[2][3] += hb.x*wv.w;
        acc[3][0] += hb.y*wv.x; acc[3][1] += hb.y*wv.y; acc[3][2] += hb.y*wv.z; acc[3][3] += hb.y*wv.w;
      }
      __syncthreads();
    }

    // ---- fold the 4x4 tile into msg accumulators ----
    if (jbase < 1024) {            // s000: msg0[w] += a0*xs0[u]*w
      const int u = (jbase >> 4) + (tx >> 2);
      const int wb = (tx & 3) << 2;
#pragma unroll
      for (int i = 0; i < 4; ++i) {
        const int le = (ty<<2) + i;
        const float cf = PW_MSG0f * a_s[le][0] * xs0_s[le][u];
#pragma unroll
        for (int cc = 0; cc < 4; ++cc)
          atomicAdd(&msg_s[le][wb+cc], cf*acc[i][cc]);
      }
    } else if (jbase < 3072) {     // s011: msg1[w][m] += a1[m]*xs0[u]*w
      const int u = ((jbase - 1024) >> 5) + (tx >> 3);
      const int wb = (tx & 7) << 2;
#pragma unroll
      for (int i = 0; i < 4; ++i) {
        const int le = (ty<<2) + i;
        const float cf = PW1f * xs0_s[le][u];
        const float b1 = a_s[le][1], b2 = a_s[le][2], b3 = a_s[le][3];
#pragma unroll
        for (int cc = 0; cc < 4; ++cc) {
          const float v = cf*acc[i][cc];
          float* mp = &msg_s[le][16 + (wb+cc)*3];
          atomicAdd(mp+0, v*b1); atomicAdd(mp+1, v*b2); atomicAdd(mp+2, v*b3);
        }
      }
    } else if (jbase < 4096) {     // s101: msg1[w][m] += a0*xs1[u][m]*w
      const int u = ((jbase - 3072) >> 5) + (tx >> 3);
      const int wb = (tx & 7) << 2;
#pragma unroll
      for (int i = 0; i < 4; ++i) {
        const int le = (ty<<2) + i;
        const float cf = PW1f * a_s[le][0];
        const float s0 = xs1_s[le][u*3], s1 = xs1_s[le][u*3+1], s2 = xs1_s[le][u*3+2];
#pragma unroll
        for (int cc = 0; cc < 4; ++cc) {
          const float v = cf*acc[i][cc];
          float* mp = &msg_s[le][16 + (wb+cc)*3];
          atomicAdd(mp+0, v*s0); atomicAdd(mp+1, v*s1); atomicAdd(mp+2, v*s2);
        }
      }
    } else {                       // s110: msg0[w] += (1/sqrt3)*z2[u]*w
      const int u = ((jbase - 4096) >> 4) + (tx >> 2);
      const int wb = (tx & 3) << 2;
#pragma unroll
      for (int i = 0; i < 4; ++i) {
        const int le = (ty<<2) + i;
        const float z2 = xs1_s[le][u*3]*a_s[le][1] + xs1_s[le][u*3+1]*a_s[le][2]
                       + xs1_s[le][u*3+2]*a_s[le][3];
        const float cf = PW_MSG0f * INV_SQRT3f * z2;
#pragma unroll
        for (int cc = 0; cc < 4; ++cc)
          atomicAdd(&msg_s[le][wb+cc], cf*acc[i][cc]);
      }
    }
  }

  __syncthreads();
  for (int i = tid; i < 32*112; i += 256) {
    int le = i / 112, slot = i - le*112;
    atomicAdd(&nm[dsts_s[le]*112 + slot], (&msg_s[0][0])[i]);
  }
}

// ---------------- K3: node gate stage -> xg ----------------
__global__ __launch_bounds__(256) void k3_gate(const float* __restrict__ x,
                                               const float* __restrict__ nm,
                                               const float* __restrict__ Wg000,
                                               const float* __restrict__ Wg110,
                                               const float* __restrict__ Wg001,
                                               const float* __restrict__ Wg111,
                                               const float* __restrict__ Wg012,
                                               const float* __restrict__ Wg102,
                                               float* __restrict__ xg,
                                               float cst_sig, float cst_tanh) {
  __shared__ float x0_s[8][64], x1_s[8][96], m0_s[8][16], m1_s[8][96];
  __shared__ float c1_s[8][1024];
  __shared__ float gate_s[8][32];
  const int tid = threadIdx.x;
  const int n0 = blockIdx.x * 8;

  for (int i = tid; i < 8*160; i += 256) {
    int n = i / 160, f = i - n*160;
    float v = x[(n0+n)*160 + f];
    if (f < 64) x0_s[n][f] = v; else x1_s[n][f-64] = v;
  }
  for (int i = tid; i < 8*112; i += 256) {
    int n = i / 112, f = i - n*112;
    float v = nm[(n0+n)*112 + f];
    if (f < 16) m0_s[n][f] = v; else m1_s[n][f-16] = v;
  }
  __syncthreads();
  for (int i = tid; i < 8192; i += 256) {
    int n = i >> 10, uv = i & 1023, u = uv >> 5, v = uv & 31;
    c1_s[n][uv] = m1_s[n][u*3]*x1_s[n][v*3] + m1_s[n][u*3+1]*x1_s[n][v*3+1]
                + m1_s[n][u*3+2]*x1_s[n][v*3+2];
  }
  __syncthreads();
  if (tid < 128) {            // gs -> xg0, w in [0,16)
    int n = tid >> 4, w = tid & 15;
    float acc1 = 0.f;
    for (int u = 0; u < 16; ++u) {
      float pv = 0.f;
      const float* wp = Wg000 + u*1024 + w;     // (u*64+v)*16+w
#pragma unroll 4
      for (int v = 0; v < 64; ++v) pv += x0_s[n][v]*wp[v*16];
      acc1 += m0_s[n][u]*pv;
    }
    float acc2 = 0.f;
    const float* c1p = c1_s[n];
#pragma unroll 4
    for (int uv = 0; uv < 1024; ++uv) acc2 += c1p[uv]*Wg110[uv*16 + w];
    float gsv = PW_G01f*(acc1 + INV_SQRT3f*acc2);
    xg[(n0+n)*112 + w] = cst_sig / (1.f + expf(-gsv));
  }
  {                            // gg -> gates, w in [0,32)
    int n = tid >> 5, w = tid & 31;
    float acc1 = 0.f;
    for (int u = 0; u < 16; ++u) {
      float pv = 0.f;
      const float* wp = Wg001 + u*2048 + w;     // (u*64+v)*32+w
#pragma unroll 4
      for (int v = 0; v < 64; ++v) pv += x0_s[n][v]*wp[v*32];
      acc1 += m0_s[n][u]*pv;
    }
    float acc2 = 0.f;
    const float* c1p = c1_s[n];
#pragma unroll 4
    for (int uv = 0; uv < 1024; ++uv) acc2 += c1p[uv]*Wg111[uv*32 + w];
    float ggv = PW_G01f*(acc1 + INV_SQRT3f*acc2);
    gate_s[n][w] = cst_tanh * tanhf(ggv);
  }
  __syncthreads();
  {                            // gv -> xg1, w in [0,32)
    int n = tid >> 5, w = tid & 31;
    float g0 = 0.f, g1 = 0.f, g2 = 0.f;
    for (int v = 0; v < 32; ++v) {
      float d = 0.f;
      const float* wp = Wg012 + v*32 + w;       // (u*32+v)*32+w
#pragma unroll 4
      for (int u = 0; u < 16; ++u) d += m0_s[n][u]*wp[u*1024];
      g0 += x1_s[n][v*3]*d; g1 += x1_s[n][v*3+1]*d; g2 += x1_s[n][v*3+2]*d;
    }
    for (int u = 0; u < 32; ++u) {
      float t = 0.f;
      const float* wp = Wg102 + u*2048 + w;     // (u*64+v)*32+w
#pragma unroll 4
      for (int v = 0; v < 64; ++v) t += x0_s[n][v]*wp[v*32];
      g0 += m1_s[n][u*3]*t; g1 += m1_s[n][u*3+1]*t; g2 += m1_s[n][u*3+2]*t;
    }
    float g = gate_s[n][w] * PW_G2f * INV_SQRT3f;
    float* o = xg + (n0+n)*112 + 16 + w*3;
    o[0] = g*g0; o[1] = g*g1; o[2] = g*g2;
  }
}

// ---------------- K4: masked canonical pooling ----------------
__global__ __launch_bounds__(256) void k4_pool(const float* __restrict__ xg,
                                               const int* __restrict__ z,
                                               const int* __restrict__ canonical,
                                               float* __restrict__ sums,
                                               float* __restrict__ cnt) {
  int idx = blockIdx.x * 256 + threadIdx.x;     // < 896000, exact
  int n = idx / 112, slot = idx - n*112;
  if (z[n] > 1) {
    int c = canonical[n];
    atomicAdd(&sums[c*112 + slot], xg[idx]);
    if (slot == 0) atomicAdd(&cnt[c], 1.f);
  }
}

// ---------------- K5: quadratic head -> th ----------------
__global__ __launch_bounds__(256) void k5_thead(const float* __restrict__ sums,
                                                const float* __restrict__ cnt,
                                                const float* __restrict__ Wa,
                                                const float* __restrict__ Wb,
                                                const float* __restrict__ Wc,
                                                const float* __restrict__ Wd,
                                                float* __restrict__ th) {
  __shared__ float xh_s[8][112];
  __shared__ float cm_s[8][1024];
  const int tid = threadIdx.x;
  const int n0 = blockIdx.x * 8;
  for (int i = tid; i < 8*112; i += 256) {
    int n = i / 112, j = i - n*112;
    float cv = fmaxf(cnt[n0+n], 1.f);
    xh_s[n][j] = sums[(n0+n)*112 + j] / cv;
  }
  __syncthreads();
  for (int i = tid; i < 8192; i += 256) {
    int n = i >> 10, uv = i & 1023, u = uv >> 5, v = uv & 31;
    const float* hh = xh_s[n] + 16;
    cm_s[n][uv] = hh[u*3]*hh[v*3] + hh[u*3+1]*hh[v*3+1] + hh[u*3+2]*hh[v*3+2];
  }
  __syncthreads();
  if (tid < 128) {             // t0, k in [0,16)
    int n = tid >> 4, k = tid & 15;
    float sA = 0.f;
    for (int v = 0; v < 16; ++v) sA += Wa[k*16+v]*xh_s[n][v];
    float wd = 0.f;
    const float* cp = cm_s[n];
#pragma unroll 4
    for (int uv = 0; uv < 1024; ++uv) wd += cp[uv]*Wd[uv*16 + k];
    th[(n0+n)*112 + k] = PW_H0f*(xh_s[n][k]*sA + INV_SQRT3f*wd);
  }
  {                             // t1, j in [0,32)
    int n = tid >> 5, j = tid & 31;
    float wb = 0.f, wc = 0.f;
    for (int u = 0; u < 16; ++u) wb += Wb[u*32+j]*xh_s[n][u];
    for (int v = 0; v < 16; ++v) wc += Wc[j*16+v]*xh_s[n][v];
    float cb = PW_H1f * INV_SQRT3f * (wb + wc);
    const float* hh = xh_s[n] + 16;
    float* o = th + (n0+n)*112 + 16 + j*3;
    o[0] = cb*hh[j*3]; o[1] = cb*hh[j*3+1]; o[2] = cb*hh[j*3+2];
  }
}

// ---------------- K6: select + output linear ----------------
__global__ __launch_bounds__(256) void k6_out(const float* __restrict__ xg,
                                              const float* __restrict__ th,
                                              const int* __restrict__ z,
                                              const int* __restrict__ canonical,
                                              const float* __restrict__ WL0,
                                              const float* __restrict__ WL1,
                                              float* __restrict__ out) {
  int idx = blockIdx.x * 256 + threadIdx.x;     // < 896000, exact
  int n = idx / 112, j = idx - n*112;
  const float* yr = (z[n] > 1) ? (th + canonical[n]*112) : (xg + n*112);
  float o = 0.f;
  if (j < 16) {
    for (int v = 0; v < 16; ++v) o += yr[v]*WL0[v*16 + j];
    o *= 0.25f;                                  // 1/sqrt(16)
  } else {
    int jj = j - 16, w = jj / 3, m = jj - w*3;
    for (int u = 0; u < 32; ++u) o += yr[16 + u*3 + m]*WL1[u*32 + w];
    o *= RSQRT32f;
  }
  out[idx] = o;
}

// ---------------- host: replicate numpy's trapz normalization constants ----
namespace {
struct Csts {
  float silu, sig, tanh_;
  Csts() {
    const int NPT = 200001;
    const double a = -12.0, b = 12.0;
    const double dx = (b - a) / (NPT - 1);
    double s1 = 0.0, s2 = 0.0, s3 = 0.0;
    for (int i = 0; i < NPT; ++i) {
      double xv = a + dx*i;
      double pdf = std::exp(-0.5*xv*xv) / std::sqrt(2.0*M_PI);
      double sg = 1.0 / (1.0 + std::exp(-xv));
      double f1 = xv*sg, f2 = sg, f3 = std::tanh(xv);
      double wg = (i == 0 || i == NPT-1) ? 0.5 : 1.0;
      s1 += wg*f1*f1*pdf; s2 += wg*f2*f2*pdf; s3 += wg*f3*f3*pdf;
    }
    silu  = (float)(1.0/std::sqrt(s1*dx));
    sig   = (float)(1.0/std::sqrt(s2*dx));
    tanh_ = (float)(1.0/std::sqrt(s3*dx));
  }
};
}  // namespace

extern "C" void kernel_launch(void* const* d_in, const int* in_sizes, int n_in,
                              void* d_out, int out_size, void* d_ws, size_t ws_size,
                              hipStream_t stream) {
  const float* x     = (const float*)d_in[0];
  const float* ea    = (const float*)d_in[1];
  const float* W1    = (const float*)d_in[2];
  const float* W2    = (const float*)d_in[3];
  const float* Wg000 = (const float*)d_in[4];
  const float* Wg110 = (const float*)d_in[5];
  const float* Wg001 = (const float*)d_in[6];
  const float* Wg111 = (const float*)d_in[7];
  const float* Wg012 = (const float*)d_in[8];
  const float* Wg102 = (const float*)d_in[9];
  const float* Wa    = (const float*)d_in[10];
  const float* Wb    = (const float*)d_in[11];
  const float* Wc    = (const float*)d_in[12];
  const float* Wd    = (const float*)d_in[13];
  const float* WL0   = (const float*)d_in[14];
  const float* WL1   = (const float*)d_in[15];
  const int* ei      = (const int*)d_in[16];
  const int* z       = (const int*)d_in[17];
  const int* canonical = (const int*)d_in[18];
  float* out = (float*)d_out;

  float* ws   = (float*)d_ws;          // needs 6,664,000 floats = 26.7 MB
  float* h    = ws;                    // 3,072,000
  float* nm   = ws + 3072000;          //   896,000
  float* xg   = ws + 3968000;          //   896,000
  float* sums = ws + 4864000;          //   896,000
  float* cnt  = ws + 5760000;          //     8,000
  float* th   = ws + 5768000;          //   896,000

  static const Csts C;                 // host-only; computed during capture

  hipMemsetAsync(nm, 0, 896000*sizeof(float), stream);
  hipMemsetAsync(sums, 0, (896000+8000)*sizeof(float), stream);

  k1_h<<<12000, 256, 0, stream>>>(ea, W1, h, C.silu);
  k2_edge_msg<<<750, 256, 0, stream>>>(x, ea, W2, h, ei, nm);
  k3_gate<<<1000, 256, 0, stream>>>(x, nm, Wg000, Wg110, Wg001, Wg111,
                                    Wg012, Wg102, xg, C.sig, C.tanh_);
  k4_pool<<<3500, 256, 0, stream>>>(xg, z, canonical, sums, cnt);
  k5_thead<<<1000, 256, 0, stream>>>(sums, cnt, Wa, Wb, Wc, Wd, th);
  k6_out<<<3500, 256, 0, stream>>>(xg, th, z, canonical, WL0, WL1, out);
}

// Round 2
// 1436.230 us; speedup vs baseline: 2.1140x; 2.1140x over previous
//
#include <hip/hip_runtime.h>
#include <hip/hip_bf16.h>
#include <cmath>

// ---------------------------------------------------------------------------
// HeavyEncoderLayer, MI355X. R2: k2 rewritten around bf16 MFMA 16x16x32.
//   k1    : h = cst*silu(ea@W1/2)/sqrt(128) -> bf16                  [trivial]
//   k_w2t : W2 [128][4608] f32 -> W2T [4608][128] bf16               [trivial]
//   k2    : per-block 32 edges: w = h @ W2 via MFMA (A=h from global,
//           B=W2T from global/L2, no main-loop barriers), fold into
//           register msg partials per region, LDS-atomic flush, scatter.
//   k3..k6: unchanged from R1 (correct; optimize next round per profile).
// ---------------------------------------------------------------------------

#define N_NODES 8000
#define N_EDGES 24000

#define INV_SQRT3f 0.57735026918962576f
#define PW_MSG0f 0.10206207261596575f   /* sqrt(1/96) */
#define PW1f     0.10206207261596575f   /* PW_MSG1*INV_SQRT3 == sqrt(1/96) */
#define PW_G01f  0.022097086912079608f  /* sqrt(1/2048) */
#define PW_G2f   0.034232659844072866f  /* sqrt(3/2560) */
#define PW_H0f   0.031008683647302115f  /* sqrt(1/1040) */
#define PW_H1f   0.30618621784789724f   /* sqrt(3/32) */
#define RSQRT128f 0.08838834764831845f
#define RSQRT32f  0.17677669529663687f

typedef short short8 __attribute__((ext_vector_type(8)));
typedef float f32x4 __attribute__((ext_vector_type(4)));

__device__ inline short f32_to_bf16_bits(float v) {
  unsigned int b = __builtin_bit_cast(unsigned int, v);
  b += 0x7fffu + ((b >> 16) & 1u);        // RNE (no NaN inputs here)
  return (short)(b >> 16);
}

// ---------------- K1: edge MLP hidden layer -> bf16 ----------------
__global__ __launch_bounds__(256) void k1_h(const float* __restrict__ ea,
                                            const float* __restrict__ W1,
                                            short* __restrict__ hbf,
                                            float cst_silu) {
  int idx = blockIdx.x * 256 + threadIdx.x;          // e*128 + r, exact grid
  int e = idx >> 7, r = idx & 127;
  float s = 0.5f * (ea[e*4+0]*W1[r] + ea[e*4+1]*W1[128+r] +
                    ea[e*4+2]*W1[256+r] + ea[e*4+3]*W1[384+r]);
  float sg = 1.f / (1.f + expf(-s));
  hbf[idx] = f32_to_bf16_bits(cst_silu * s * sg * RSQRT128f);
}

// ---------------- W2 -> W2T bf16 [4608][128] ----------------
__global__ __launch_bounds__(256) void k_w2t(const float* __restrict__ W2,
                                             short* __restrict__ w2t) {
  int idx = blockIdx.x * 256 + threadIdx.x;          // 589824 exact
  int c = idx >> 7, k = idx & 127;
  w2t[idx] = f32_to_bf16_bits(W2[k*4608 + c]);
}

// ---------------- K2: MFMA edge GEMM + tensor-product fold + scatter -------
// Block = 256 thr = 4 waves, 32 edges. A = h[32][128] bf16 (regs, 32 VGPR).
// N-tiles (16 cols) split across waves; per tile: 4 B-frag global loads,
// 8 MFMA (2 m-tiles x 4 k-steps), fold into register partials.
// C/D layout: col = lane&15, row = quad*4+reg (m89). Region cols:
//   000: u*16+w          110: 4096+u*16+w
//   011: 1024+u*32+w     101: 3072+u*32+w
__global__ __launch_bounds__(256) void k2_edge_msg(const float* __restrict__ x,
                                                   const float* __restrict__ ea,
                                                   const short* __restrict__ w2t,
                                                   const short* __restrict__ hbf,
                                                   const int* __restrict__ ei,
                                                   float* __restrict__ nm) {
  __shared__ float msg_s[32][112];
  __shared__ float cf000t[64][32];     // [u][e] PW0*a0*xs0
  __shared__ float x0pt[64][32];       // [u][e] PW1*xs0
  __shared__ float z2wt[32][32];       // [u][e] PW0*inv3*(xs1[u].a1)
  __shared__ float x1wt[32][32][4];    // [u][e][m] PW1*a0*xs1[u][m]
  __shared__ float a_s[32][4];
  __shared__ int srcs_s[32], dsts_s[32];

  const int tid = threadIdx.x;
  const int e0 = blockIdx.x * 32;

  if (tid < 32) { srcs_s[tid] = ei[e0+tid]; dsts_s[tid] = ei[N_EDGES + e0 + tid]; }
  if (tid < 128) a_s[tid>>2][tid&3] = ea[e0*4 + tid];
  for (int i = tid; i < 32*112; i += 256) (&msg_s[0][0])[i] = 0.f;
  __syncthreads();

  for (int i = tid; i < 2048; i += 256) {      // coalesced x0 gather
    int e = i >> 6, u = i & 63;
    float v = x[srcs_s[e]*160 + u];
    cf000t[u][e] = PW_MSG0f * a_s[e][0] * v;
    x0pt[u][e]   = PW1f * v;
  }
  for (int i = tid; i < 1024; i += 256) {
    int e = i >> 5, u = i & 31;
    const float* xp = &x[srcs_s[e]*160 + 64 + u*3];
    float m0v = xp[0], m1v = xp[1], m2v = xp[2];
    float a0 = a_s[e][0];
    z2wt[u][e] = PW_MSG0f * INV_SQRT3f *
                 (m0v*a_s[e][1] + m1v*a_s[e][2] + m2v*a_s[e][3]);
    x1wt[u][e][0] = PW1f * a0 * m0v;
    x1wt[u][e][1] = PW1f * a0 * m1v;
    x1wt[u][e][2] = PW1f * a0 * m2v;
    x1wt[u][e][3] = 0.f;
  }
  __syncthreads();

  const int lane = tid & 63, wv = tid >> 6;
  const int quad = lane >> 4, nn = lane & 15;
  const int eq = quad * 4;               // base C-row (edge-in-mtile)

  // A fragments: h for 32 edges, all of K, straight from global (L2).
  short8 af[2][4];
#pragma unroll
  for (int t = 0; t < 2; ++t)
#pragma unroll
    for (int ks = 0; ks < 4; ++ks)
      af[t][ks] = *(const short8*)&hbf[(e0 + t*16 + nn)*128 + ks*32 + quad*8];

  float p0[2][4] = {};        // msg0[e][nn]
  float p011[2][4] = {};      // msg1 xs0-side, w = (wv&1)*16+nn
  float p101[2][4][3] = {};   // msg1 xs1-side, same w

#define GEMM_TILE(BP)                                                         \
  const short8 b0 = *(const short8*)(BP);                                     \
  const short8 b1 = *(const short8*)((BP) + 32);                              \
  const short8 b2 = *(const short8*)((BP) + 64);                              \
  const short8 b3 = *(const short8*)((BP) + 96);                              \
  f32x4 c0 = {0.f,0.f,0.f,0.f}, c1 = {0.f,0.f,0.f,0.f};                       \
  c0 = __builtin_amdgcn_mfma_f32_16x16x32_bf16(af[0][0], b0, c0, 0,0,0);      \
  c1 = __builtin_amdgcn_mfma_f32_16x16x32_bf16(af[1][0], b0, c1, 0,0,0);      \
  c0 = __builtin_amdgcn_mfma_f32_16x16x32_bf16(af[0][1], b1, c0, 0,0,0);      \
  c1 = __builtin_amdgcn_mfma_f32_16x16x32_bf16(af[1][1], b1, c1, 0,0,0);      \
  c0 = __builtin_amdgcn_mfma_f32_16x16x32_bf16(af[0][2], b2, c0, 0,0,0);      \
  c1 = __builtin_amdgcn_mfma_f32_16x16x32_bf16(af[1][2], b2, c1, 0,0,0);      \
  c0 = __builtin_amdgcn_mfma_f32_16x16x32_bf16(af[0][3], b3, c0, 0,0,0);      \
  c1 = __builtin_amdgcn_mfma_f32_16x16x32_bf16(af[1][3], b3, c1, 0,0,0);

  // region 000: 64 tiles
  for (int u = wv; u < 64; u += 4) {
    const short* bp = &w2t[(u*16 + nn)*128 + quad*8];
    GEMM_TILE(bp)
    const f32x4 w0 = *(const f32x4*)&cf000t[u][eq];
    const f32x4 w1 = *(const f32x4*)&cf000t[u][16 + eq];
#pragma unroll
    for (int r = 0; r < 4; ++r) { p0[0][r] += w0[r]*c0[r]; p0[1][r] += w1[r]*c1[r]; }
  }
  // region 110: 32 tiles (also msg0)
  for (int u = wv; u < 32; u += 4) {
    const short* bp = &w2t[(4096 + u*16 + nn)*128 + quad*8];
    GEMM_TILE(bp)
    const f32x4 w0 = *(const f32x4*)&z2wt[u][eq];
    const f32x4 w1 = *(const f32x4*)&z2wt[u][16 + eq];
#pragma unroll
    for (int r = 0; r < 4; ++r) { p0[0][r] += w0[r]*c0[r]; p0[1][r] += w1[r]*c1[r]; }
  }
  // region 011: 128 tiles (wb = wv&1 fixed per wave)
  for (int idx = wv; idx < 128; idx += 4) {
    const int u = idx >> 1, wb = idx & 1;
    const short* bp = &w2t[(1024 + u*32 + wb*16 + nn)*128 + quad*8];
    GEMM_TILE(bp)
    const f32x4 w0 = *(const f32x4*)&x0pt[u][eq];
    const f32x4 w1 = *(const f32x4*)&x0pt[u][16 + eq];
#pragma unroll
    for (int r = 0; r < 4; ++r) { p011[0][r] += w0[r]*c0[r]; p011[1][r] += w1[r]*c1[r]; }
  }
  // region 101: 64 tiles (wb = wv&1 fixed per wave)
  for (int idx = wv; idx < 64; idx += 4) {
    const int u = idx >> 1, wb = idx & 1;
    const short* bp = &w2t[(3072 + u*32 + wb*16 + nn)*128 + quad*8];
    GEMM_TILE(bp)
#pragma unroll
    for (int r = 0; r < 4; ++r) {
      const f32x4 xw0 = *(const f32x4*)&x1wt[u][eq + r][0];
      const f32x4 xw1 = *(const f32x4*)&x1wt[u][16 + eq + r][0];
      p101[0][r][0] += xw0[0]*c0[r]; p101[0][r][1] += xw0[1]*c0[r]; p101[0][r][2] += xw0[2]*c0[r];
      p101[1][r][0] += xw1[0]*c1[r]; p101[1][r][1] += xw1[1]*c1[r]; p101[1][r][2] += xw1[2]*c1[r];
    }
  }
#undef GEMM_TILE

  // flush register partials -> msg_s (cross-wave accumulate)
  const int wcol = (wv & 1)*16 + nn;
#pragma unroll
  for (int t = 0; t < 2; ++t)
#pragma unroll
    for (int r = 0; r < 4; ++r) {
      const int e = t*16 + eq + r;
      atomicAdd(&msg_s[e][nn], p0[t][r]);
      const float q = p011[t][r];
      atomicAdd(&msg_s[e][16 + wcol*3 + 0], a_s[e][1]*q + p101[t][r][0]);
      atomicAdd(&msg_s[e][16 + wcol*3 + 1], a_s[e][2]*q + p101[t][r][1]);
      atomicAdd(&msg_s[e][16 + wcol*3 + 2], a_s[e][3]*q + p101[t][r][2]);
    }
  __syncthreads();

  for (int i = tid; i < 32*112; i += 256) {
    int le = i / 112, slot = i - le*112;
    atomicAdd(&nm[dsts_s[le]*112 + slot], (&msg_s[0][0])[i]);
  }
}

// ---------------- K3: node gate stage -> xg ----------------
__global__ __launch_bounds__(256) void k3_gate(const float* __restrict__ x,
                                               const float* __restrict__ nm,
                                               const float* __restrict__ Wg000,
                                               const float* __restrict__ Wg110,
                                               const float* __restrict__ Wg001,
                                               const float* __restrict__ Wg111,
                                               const float* __restrict__ Wg012,
                                               const float* __restrict__ Wg102,
                                               float* __restrict__ xg,
                                               float cst_sig, float cst_tanh) {
  __shared__ float x0_s[8][64], x1_s[8][96], m0_s[8][16], m1_s[8][96];
  __shared__ float c1_s[8][1024];
  __shared__ float gate_s[8][32];
  const int tid = threadIdx.x;
  const int n0 = blockIdx.x * 8;

  for (int i = tid; i < 8*160; i += 256) {
    int n = i / 160, f = i - n*160;
    float v = x[(n0+n)*160 + f];
    if (f < 64) x0_s[n][f] = v; else x1_s[n][f-64] = v;
  }
  for (int i = tid; i < 8*112; i += 256) {
    int n = i / 112, f = i - n*112;
    float v = nm[(n0+n)*112 + f];
    if (f < 16) m0_s[n][f] = v; else m1_s[n][f-16] = v;
  }
  __syncthreads();
  for (int i = tid; i < 8192; i += 256) {
    int n = i >> 10, uv = i & 1023, u = uv >> 5, v = uv & 31;
    c1_s[n][uv] = m1_s[n][u*3]*x1_s[n][v*3] + m1_s[n][u*3+1]*x1_s[n][v*3+1]
                + m1_s[n][u*3+2]*x1_s[n][v*3+2];
  }
  __syncthreads();
  if (tid < 128) {            // gs -> xg0, w in [0,16)
    int n = tid >> 4, w = tid & 15;
    float acc1 = 0.f;
    for (int u = 0; u < 16; ++u) {
      float pv = 0.f;
      const float* wp = Wg000 + u*1024 + w;
#pragma unroll 4
      for (int v = 0; v < 64; ++v) pv += x0_s[n][v]*wp[v*16];
      acc1 += m0_s[n][u]*pv;
    }
    float acc2 = 0.f;
    const float* c1p = c1_s[n];
#pragma unroll 4
    for (int uv = 0; uv < 1024; ++uv) acc2 += c1p[uv]*Wg110[uv*16 + w];
    float gsv = PW_G01f*(acc1 + INV_SQRT3f*acc2);
    xg[(n0+n)*112 + w] = cst_sig / (1.f + expf(-gsv));
  }
  {                            // gg -> gates, w in [0,32)
    int n = tid >> 5, w = tid & 31;
    float acc1 = 0.f;
    for (int u = 0; u < 16; ++u) {
      float pv = 0.f;
      const float* wp = Wg001 + u*2048 + w;
#pragma unroll 4
      for (int v = 0; v < 64; ++v) pv += x0_s[n][v]*wp[v*32];
      acc1 += m0_s[n][u]*pv;
    }
    float acc2 = 0.f;
    const float* c1p = c1_s[n];
#pragma unroll 4
    for (int uv = 0; uv < 1024; ++uv) acc2 += c1p[uv]*Wg111[uv*32 + w];
    float ggv = PW_G01f*(acc1 + INV_SQRT3f*acc2);
    gate_s[n][w] = cst_tanh * tanhf(ggv);
  }
  __syncthreads();
  {                            // gv -> xg1, w in [0,32)
    int n = tid >> 5, w = tid & 31;
    float g0 = 0.f, g1 = 0.f, g2 = 0.f;
    for (int v = 0; v < 32; ++v) {
      float d = 0.f;
      const float* wp = Wg012 + v*32 + w;
#pragma unroll 4
      for (int u = 0; u < 16; ++u) d += m0_s[n][u]*wp[u*1024];
      g0 += x1_s[n][v*3]*d; g1 += x1_s[n][v*3+1]*d; g2 += x1_s[n][v*3+2]*d;
    }
    for (int u = 0; u < 32; ++u) {
      float t = 0.f;
      const float* wp = Wg102 + u*2048 + w;
#pragma unroll 4
      for (int v = 0; v < 64; ++v) t += x0_s[n][v]*wp[v*32];
      g0 += m1_s[n][u*3]*t; g1 += m1_s[n][u*3+1]*t; g2 += m1_s[n][u*3+2]*t;
    }
    float g = gate_s[n][w] * PW_G2f * INV_SQRT3f;
    float* o = xg + (n0+n)*112 + 16 + w*3;
    o[0] = g*g0; o[1] = g*g1; o[2] = g*g2;
  }
}

// ---------------- K4: masked canonical pooling ----------------
__global__ __launch_bounds__(256) void k4_pool(const float* __restrict__ xg,
                                               const int* __restrict__ z,
                                               const int* __restrict__ canonical,
                                               float* __restrict__ sums,
                                               float* __restrict__ cnt) {
  int idx = blockIdx.x * 256 + threadIdx.x;
  int n = idx / 112, slot = idx - n*112;
  if (z[n] > 1) {
    int c = canonical[n];
    atomicAdd(&sums[c*112 + slot], xg[idx]);
    if (slot == 0) atomicAdd(&cnt[c], 1.f);
  }
}

// ---------------- K5: quadratic head -> th ----------------
__global__ __launch_bounds__(256) void k5_thead(const float* __restrict__ sums,
                                                const float* __restrict__ cnt,
                                                const float* __restrict__ Wa,
                                                const float* __restrict__ Wb,
                                                const float* __restrict__ Wc,
                                                const float* __restrict__ Wd,
                                                float* __restrict__ th) {
  __shared__ float xh_s[8][112];
  __shared__ float cm_s[8][1024];
  const int tid = threadIdx.x;
  const int n0 = blockIdx.x * 8;
  for (int i = tid; i < 8*112; i += 256) {
    int n = i / 112, j = i - n*112;
    float cv = fmaxf(cnt[n0+n], 1.f);
    xh_s[n][j] = sums[(n0+n)*112 + j] / cv;
  }
  __syncthreads();
  for (int i = tid; i < 8192; i += 256) {
    int n = i >> 10, uv = i & 1023, u = uv >> 5, v = uv & 31;
    const float* hh = xh_s[n] + 16;
    cm_s[n][uv] = hh[u*3]*hh[v*3] + hh[u*3+1]*hh[v*3+1] + hh[u*3+2]*hh[v*3+2];
  }
  __syncthreads();
  if (tid < 128) {
    int n = tid >> 4, k = tid & 15;
    float sA = 0.f;
    for (int v = 0; v < 16; ++v) sA += Wa[k*16+v]*xh_s[n][v];
    float wd = 0.f;
    const float* cp = cm_s[n];
#pragma unroll 4
    for (int uv = 0; uv < 1024; ++uv) wd += cp[uv]*Wd[uv*16 + k];
    th[(n0+n)*112 + k] = PW_H0f*(xh_s[n][k]*sA + INV_SQRT3f*wd);
  }
  {
    int n = tid >> 5, j = tid & 31;
    float wb = 0.f, wc = 0.f;
    for (int u = 0; u < 16; ++u) wb += Wb[u*32+j]*xh_s[n][u];
    for (int v = 0; v < 16; ++v) wc += Wc[j*16+v]*xh_s[n][v];
    float cb = PW_H1f * INV_SQRT3f * (wb + wc);
    const float* hh = xh_s[n] + 16;
    float* o = th + (n0+n)*112 + 16 + j*3;
    o[0] = cb*hh[j*3]; o[1] = cb*hh[j*3+1]; o[2] = cb*hh[j*3+2];
  }
}

// ---------------- K6: select + output linear ----------------
__global__ __launch_bounds__(256) void k6_out(const float* __restrict__ xg,
                                              const float* __restrict__ th,
                                              const int* __restrict__ z,
                                              const int* __restrict__ canonical,
                                              const float* __restrict__ WL0,
                                              const float* __restrict__ WL1,
                                              float* __restrict__ out) {
  int idx = blockIdx.x * 256 + threadIdx.x;
  int n = idx / 112, j = idx - n*112;
  const float* yr = (z[n] > 1) ? (th + canonical[n]*112) : (xg + n*112);
  float o = 0.f;
  if (j < 16) {
    for (int v = 0; v < 16; ++v) o += yr[v]*WL0[v*16 + j];
    o *= 0.25f;
  } else {
    int jj = j - 16, w = jj / 3, m = jj - w*3;
    for (int u = 0; u < 32; ++u) o += yr[16 + u*3 + m]*WL1[u*32 + w];
    o *= RSQRT32f;
  }
  out[idx] = o;
}

// ---------------- host: replicate numpy's trapz normalization constants ----
namespace {
struct Csts {
  float silu, sig, tanh_;
  Csts() {
    const int NPT = 200001;
    const double a = -12.0, b = 12.0;
    const double dx = (b - a) / (NPT - 1);
    double s1 = 0.0, s2 = 0.0, s3 = 0.0;
    for (int i = 0; i < NPT; ++i) {
      double xv = a + dx*i;
      double pdf = std::exp(-0.5*xv*xv) / std::sqrt(2.0*M_PI);
      double sg = 1.0 / (1.0 + std::exp(-xv));
      double f1 = xv*sg, f2 = sg, f3 = std::tanh(xv);
      double wg = (i == 0 || i == NPT-1) ? 0.5 : 1.0;
      s1 += wg*f1*f1*pdf; s2 += wg*f2*f2*pdf; s3 += wg*f3*f3*pdf;
    }
    silu  = (float)(1.0/std::sqrt(s1*dx));
    sig   = (float)(1.0/std::sqrt(s2*dx));
    tanh_ = (float)(1.0/std::sqrt(s3*dx));
  }
};
}  // namespace

extern "C" void kernel_launch(void* const* d_in, const int* in_sizes, int n_in,
                              void* d_out, int out_size, void* d_ws, size_t ws_size,
                              hipStream_t stream) {
  const float* x     = (const float*)d_in[0];
  const float* ea    = (const float*)d_in[1];
  const float* W1    = (const float*)d_in[2];
  const float* W2    = (const float*)d_in[3];
  const float* Wg000 = (const float*)d_in[4];
  const float* Wg110 = (const float*)d_in[5];
  const float* Wg001 = (const float*)d_in[6];
  const float* Wg111 = (const float*)d_in[7];
  const float* Wg012 = (const float*)d_in[8];
  const float* Wg102 = (const float*)d_in[9];
  const float* Wa    = (const float*)d_in[10];
  const float* Wb    = (const float*)d_in[11];
  const float* Wc    = (const float*)d_in[12];
  const float* Wd    = (const float*)d_in[13];
  const float* WL0   = (const float*)d_in[14];
  const float* WL1   = (const float*)d_in[15];
  const int* ei      = (const int*)d_in[16];
  const int* z       = (const int*)d_in[17];
  const int* canonical = (const int*)d_in[18];
  float* out = (float*)d_out;

  float* ws   = (float*)d_ws;          // 5,423,000 floats = 21.7 MB
  short* hbf  = (short*)ws;            // 3,072,000 bf16 -> 1,536,000 f-slots
  short* w2t  = (short*)(ws + 1536000);//   589,824 bf16 ->   295,000 f-slots
  float* nm   = ws + 1831000;          //   896,000
  float* xg   = ws + 2727000;          //   896,000
  float* sums = ws + 3623000;          //   896,000
  float* cnt  = ws + 4519000;          //     8,000 (contiguous after sums)
  float* th   = ws + 4527000;          //   896,000

  static const Csts C;                 // host-only; safe under graph capture

  hipMemsetAsync(nm, 0, 896000*sizeof(float), stream);
  hipMemsetAsync(sums, 0, (896000+8000)*sizeof(float), stream);

  k1_h<<<12000, 256, 0, stream>>>(ea, W1, hbf, C.silu);
  k_w2t<<<2304, 256, 0, stream>>>(W2, w2t);
  k2_edge_msg<<<750, 256, 0, stream>>>(x, ea, w2t, hbf, ei, nm);
  k3_gate<<<1000, 256, 0, stream>>>(x, nm, Wg000, Wg110, Wg001, Wg111,
                                    Wg012, Wg102, xg, C.sig, C.tanh_);
  k4_pool<<<3500, 256, 0, stream>>>(xg, z, canonical, sums, cnt);
  k5_thead<<<1000, 256, 0, stream>>>(sums, cnt, Wa, Wb, Wc, Wd, th);
  k6_out<<<3500, 256, 0, stream>>>(xg, th, z, canonical, WL0, WL1, out);
}

// Round 3
// 388.959 us; speedup vs baseline: 7.8061x; 3.6925x over previous
//
#include <hip/hip_runtime.h>
#include <hip/hip_bf16.h>
#include <cmath>

// ---------------------------------------------------------------------------
// HeavyEncoderLayer, MI355X. R3: k3 rewritten as bf16-MFMA node-batched GEMMs
// (x-side-first factoring), B-tables prepped in bf16 [col][k] layout, folds
// against m0/m1/x1 done per-tile in registers (k2's proven structure).
// ---------------------------------------------------------------------------

#define N_NODES 8000
#define N_EDGES 24000

#define INV_SQRT3f 0.57735026918962576f
#define PW_MSG0f 0.10206207261596575f   /* sqrt(1/96) */
#define PW1f     0.10206207261596575f   /* PW_MSG1*INV_SQRT3 == sqrt(1/96) */
#define PW_G01f  0.022097086912079608f  /* sqrt(1/2048) */
#define PW_G2f   0.034232659844072866f  /* sqrt(3/2560) */
#define PW_H0f   0.031008683647302115f  /* sqrt(1/1040) */
#define PW_H1f   0.30618621784789724f   /* sqrt(3/32) */
#define RSQRT128f 0.08838834764831845f
#define RSQRT32f  0.17677669529663687f

typedef short short8 __attribute__((ext_vector_type(8)));
typedef float f32x4 __attribute__((ext_vector_type(4)));

__device__ inline short f32_to_bf16_bits(float v) {
  unsigned int b = __builtin_bit_cast(unsigned int, v);
  b += 0x7fffu + ((b >> 16) & 1u);        // RNE (no NaN inputs here)
  return (short)(b >> 16);
}

// ---------------- K1: edge MLP hidden layer -> bf16 ----------------
__global__ __launch_bounds__(256) void k1_h(const float* __restrict__ ea,
                                            const float* __restrict__ W1,
                                            short* __restrict__ hbf,
                                            float cst_silu) {
  int idx = blockIdx.x * 256 + threadIdx.x;          // e*128 + r, exact grid
  int e = idx >> 7, r = idx & 127;
  float s = 0.5f * (ea[e*4+0]*W1[r] + ea[e*4+1]*W1[128+r] +
                    ea[e*4+2]*W1[256+r] + ea[e*4+3]*W1[384+r]);
  float sg = 1.f / (1.f + expf(-s));
  hbf[idx] = f32_to_bf16_bits(cst_silu * s * sg * RSQRT128f);
}

// ---------------- W2 -> W2T bf16 [4608][128] ----------------
__global__ __launch_bounds__(256) void k_w2t(const float* __restrict__ W2,
                                             short* __restrict__ w2t) {
  int idx = blockIdx.x * 256 + threadIdx.x;          // 589824 exact
  int c = idx >> 7, k = idx & 127;
  w2t[idx] = f32_to_bf16_bits(W2[k*4608 + c]);
}

// ---------------- Wg* -> bf16 B-tables [col][k] for k3 ----------------
// b000 [u*16+w][v]   K=64  16384 @ 0
// b001 [u*32+w][v]   K=64  32768 @ 16384
// b110 [u*16+w][v]   K=32  16384 @ 49152   (scaled INV_SQRT3)
// b111 [u*32+w][v]   K=32  32768 @ 65536   (scaled INV_SQRT3)
// b012 [v*32+w][u]   K=32  32768 @ 98304   (u>=16 zero-padded)
// b102 [u*32+w][v]   K=64  65536 @ 131072
__global__ __launch_bounds__(256) void k_wgt(const float* __restrict__ Wg000,
                                             const float* __restrict__ Wg110,
                                             const float* __restrict__ Wg001,
                                             const float* __restrict__ Wg111,
                                             const float* __restrict__ Wg012,
                                             const float* __restrict__ Wg102,
                                             short* __restrict__ bt) {
  int i = blockIdx.x * 256 + threadIdx.x;            // < 196608 exact
  float v;
  if (i < 16384) {
    int col = i >> 6, vv = i & 63, u = col >> 4, w = col & 15;
    v = Wg000[u*1024 + vv*16 + w];
  } else if (i < 49152) {
    int j = i - 16384; int col = j >> 6, vv = j & 63, u = col >> 5, w = col & 31;
    v = Wg001[u*2048 + vv*32 + w];
  } else if (i < 65536) {
    int j = i - 49152; int col = j >> 5, vv = j & 31, u = col >> 4, w = col & 15;
    v = INV_SQRT3f * Wg110[u*512 + vv*16 + w];
  } else if (i < 98304) {
    int j = i - 65536; int col = j >> 5, vv = j & 31, u = col >> 5, w = col & 31;
    v = INV_SQRT3f * Wg111[u*1024 + vv*32 + w];
  } else if (i < 131072) {
    int j = i - 98304; int col = j >> 5, u = j & 31, vv = col >> 5, w = col & 31;
    v = (u < 16) ? Wg012[u*1024 + vv*32 + w] : 0.f;
  } else {
    int j = i - 131072; int col = j >> 6, vv = j & 63, u = col >> 5, w = col & 31;
    v = Wg102[u*2048 + vv*32 + w];
  }
  bt[i] = f32_to_bf16_bits(v);
}

// ---------------- K2: MFMA edge GEMM + tensor-product fold + scatter -------
__global__ __launch_bounds__(256) void k2_edge_msg(const float* __restrict__ x,
                                                   const float* __restrict__ ea,
                                                   const short* __restrict__ w2t,
                                                   const short* __restrict__ hbf,
                                                   const int* __restrict__ ei,
                                                   float* __restrict__ nm) {
  __shared__ float msg_s[32][112];
  __shared__ float cf000t[64][32];     // [u][e] PW0*a0*xs0
  __shared__ float x0pt[64][32];       // [u][e] PW1*xs0
  __shared__ float z2wt[32][32];       // [u][e] PW0*inv3*(xs1[u].a1)
  __shared__ float x1wt[32][32][4];    // [u][e][m] PW1*a0*xs1[u][m]
  __shared__ float a_s[32][4];
  __shared__ int srcs_s[32], dsts_s[32];

  const int tid = threadIdx.x;
  const int e0 = blockIdx.x * 32;

  if (tid < 32) { srcs_s[tid] = ei[e0+tid]; dsts_s[tid] = ei[N_EDGES + e0 + tid]; }
  if (tid < 128) a_s[tid>>2][tid&3] = ea[e0*4 + tid];
  for (int i = tid; i < 32*112; i += 256) (&msg_s[0][0])[i] = 0.f;
  __syncthreads();

  for (int i = tid; i < 2048; i += 256) {      // coalesced x0 gather
    int e = i >> 6, u = i & 63;
    float v = x[srcs_s[e]*160 + u];
    cf000t[u][e] = PW_MSG0f * a_s[e][0] * v;
    x0pt[u][e]   = PW1f * v;
  }
  for (int i = tid; i < 1024; i += 256) {
    int e = i >> 5, u = i & 31;
    const float* xp = &x[srcs_s[e]*160 + 64 + u*3];
    float m0v = xp[0], m1v = xp[1], m2v = xp[2];
    float a0 = a_s[e][0];
    z2wt[u][e] = PW_MSG0f * INV_SQRT3f *
                 (m0v*a_s[e][1] + m1v*a_s[e][2] + m2v*a_s[e][3]);
    x1wt[u][e][0] = PW1f * a0 * m0v;
    x1wt[u][e][1] = PW1f * a0 * m1v;
    x1wt[u][e][2] = PW1f * a0 * m2v;
    x1wt[u][e][3] = 0.f;
  }
  __syncthreads();

  const int lane = tid & 63, wv = tid >> 6;
  const int quad = lane >> 4, nn = lane & 15;
  const int eq = quad * 4;

  short8 af[2][4];
#pragma unroll
  for (int t = 0; t < 2; ++t)
#pragma unroll
    for (int ks = 0; ks < 4; ++ks)
      af[t][ks] = *(const short8*)&hbf[(e0 + t*16 + nn)*128 + ks*32 + quad*8];

  float p0[2][4] = {};
  float p011[2][4] = {};
  float p101[2][4][3] = {};

#define GEMM_TILE(BP)                                                         \
  const short8 b0 = *(const short8*)(BP);                                     \
  const short8 b1 = *(const short8*)((BP) + 32);                              \
  const short8 b2 = *(const short8*)((BP) + 64);                              \
  const short8 b3 = *(const short8*)((BP) + 96);                              \
  f32x4 c0 = {0.f,0.f,0.f,0.f}, c1 = {0.f,0.f,0.f,0.f};                       \
  c0 = __builtin_amdgcn_mfma_f32_16x16x32_bf16(af[0][0], b0, c0, 0,0,0);      \
  c1 = __builtin_amdgcn_mfma_f32_16x16x32_bf16(af[1][0], b0, c1, 0,0,0);      \
  c0 = __builtin_amdgcn_mfma_f32_16x16x32_bf16(af[0][1], b1, c0, 0,0,0);      \
  c1 = __builtin_amdgcn_mfma_f32_16x16x32_bf16(af[1][1], b1, c1, 0,0,0);      \
  c0 = __builtin_amdgcn_mfma_f32_16x16x32_bf16(af[0][2], b2, c0, 0,0,0);      \
  c1 = __builtin_amdgcn_mfma_f32_16x16x32_bf16(af[1][2], b2, c1, 0,0,0);      \
  c0 = __builtin_amdgcn_mfma_f32_16x16x32_bf16(af[0][3], b3, c0, 0,0,0);      \
  c1 = __builtin_amdgcn_mfma_f32_16x16x32_bf16(af[1][3], b3, c1, 0,0,0);

  for (int u = wv; u < 64; u += 4) {
    const short* bp = &w2t[(u*16 + nn)*128 + quad*8];
    GEMM_TILE(bp)
    const f32x4 w0 = *(const f32x4*)&cf000t[u][eq];
    const f32x4 w1 = *(const f32x4*)&cf000t[u][16 + eq];
#pragma unroll
    for (int r = 0; r < 4; ++r) { p0[0][r] += w0[r]*c0[r]; p0[1][r] += w1[r]*c1[r]; }
  }
  for (int u = wv; u < 32; u += 4) {
    const short* bp = &w2t[(4096 + u*16 + nn)*128 + quad*8];
    GEMM_TILE(bp)
    const f32x4 w0 = *(const f32x4*)&z2wt[u][eq];
    const f32x4 w1 = *(const f32x4*)&z2wt[u][16 + eq];
#pragma unroll
    for (int r = 0; r < 4; ++r) { p0[0][r] += w0[r]*c0[r]; p0[1][r] += w1[r]*c1[r]; }
  }
  for (int idx = wv; idx < 128; idx += 4) {
    const int u = idx >> 1, wb = idx & 1;
    const short* bp = &w2t[(1024 + u*32 + wb*16 + nn)*128 + quad*8];
    GEMM_TILE(bp)
    const f32x4 w0 = *(const f32x4*)&x0pt[u][eq];
    const f32x4 w1 = *(const f32x4*)&x0pt[u][16 + eq];
#pragma unroll
    for (int r = 0; r < 4; ++r) { p011[0][r] += w0[r]*c0[r]; p011[1][r] += w1[r]*c1[r]; }
  }
  for (int idx = wv; idx < 64; idx += 4) {
    const int u = idx >> 1, wb = idx & 1;
    const short* bp = &w2t[(3072 + u*32 + wb*16 + nn)*128 + quad*8];
    GEMM_TILE(bp)
#pragma unroll
    for (int r = 0; r < 4; ++r) {
      const f32x4 xw0 = *(const f32x4*)&x1wt[u][eq + r][0];
      const f32x4 xw1 = *(const f32x4*)&x1wt[u][16 + eq + r][0];
      p101[0][r][0] += xw0[0]*c0[r]; p101[0][r][1] += xw0[1]*c0[r]; p101[0][r][2] += xw0[2]*c0[r];
      p101[1][r][0] += xw1[0]*c1[r]; p101[1][r][1] += xw1[1]*c1[r]; p101[1][r][2] += xw1[2]*c1[r];
    }
  }
#undef GEMM_TILE

  const int wcol = (wv & 1)*16 + nn;
#pragma unroll
  for (int t = 0; t < 2; ++t)
#pragma unroll
    for (int r = 0; r < 4; ++r) {
      const int e = t*16 + eq + r;
      atomicAdd(&msg_s[e][nn], p0[t][r]);
      const float q = p011[t][r];
      atomicAdd(&msg_s[e][16 + wcol*3 + 0], a_s[e][1]*q + p101[t][r][0]);
      atomicAdd(&msg_s[e][16 + wcol*3 + 1], a_s[e][2]*q + p101[t][r][1]);
      atomicAdd(&msg_s[e][16 + wcol*3 + 2], a_s[e][3]*q + p101[t][r][2]);
    }
  __syncthreads();

  for (int i = tid; i < 32*112; i += 256) {
    int le = i / 112, slot = i - le*112;
    atomicAdd(&nm[dsts_s[le]*112 + slot], (&msg_s[0][0])[i]);
  }
}

// ---------------- K3: node gate stage via MFMA -> xg ----------------
// 16 nodes/block, 4 waves. A-frags (x0,x1_m,m0) in registers from LDS;
// B-frags from L2-resident bf16 tables; per-tile register fold against
// transposed f32 coefficient tables; LDS-atomic combine; epilogue.
__global__ __launch_bounds__(256) void k3_gate(const float* __restrict__ x,
                                               const float* __restrict__ nm,
                                               const short* __restrict__ bt,
                                               float* __restrict__ xg,
                                               float cst_sig, float cst_tanh) {
  __shared__ short x0b[16][64];       // bf16 A: x0
  __shared__ short x1b[3][16][32];    // bf16 A: x1 per m
  __shared__ short m0b[16][32];       // bf16 A: m0 (K-padded with zeros)
  __shared__ float m0t[16][16];       // [u][n] fold coeff
  __shared__ float m1t[32][3][16];    // [u][m][n]
  __shared__ float x1t[32][3][16];    // [v][m][n]
  __shared__ float gs_s[16][16];
  __shared__ float gg_s[16][32];
  __shared__ float gv_s[16][96];      // [n][w*3+m]
  const int tid = threadIdx.x;
  const int n0 = blockIdx.x * 16;

  for (int i = tid; i < 16*160; i += 256) {
    int n = i / 160, f = i - n*160;
    float v = x[(n0+n)*160 + f];
    if (f < 64) x0b[n][f] = f32_to_bf16_bits(v);
    else {
      int j = f - 64; int vv = j/3, m = j - vv*3;
      x1b[m][n][vv] = f32_to_bf16_bits(v);
      x1t[vv][m][n] = v;
    }
  }
  for (int i = tid; i < 16*112; i += 256) {
    int n = i / 112, f = i - n*112;
    float v = nm[(n0+n)*112 + f];
    if (f < 16) { m0b[n][f] = f32_to_bf16_bits(v); m0t[f][n] = v; }
    else { int j = f - 16; int u = j/3, m = j - u*3; m1t[u][m][n] = v; }
  }
  { int n = tid >> 4, k = tid & 15; m0b[n][16+k] = 0; }   // K-pad zeros
  (&gs_s[0][0])[tid] = 0.f;                               // 256 exact
  for (int i = tid; i < 512; i += 256) (&gg_s[0][0])[i] = 0.f;
  for (int i = tid; i < 1536; i += 256) (&gv_s[0][0])[i] = 0.f;
  __syncthreads();

  const int lane = tid & 63, wv = tid >> 6;
  const int quad = lane >> 4, nn = lane & 15;
  const int eq = quad * 4;
  const int wh = wv & 1;

  const short8 ax0a = *(const short8*)&x0b[nn][quad*8];
  const short8 ax0c = *(const short8*)&x0b[nn][32 + quad*8];
  short8 ax1[3];
#pragma unroll
  for (int m = 0; m < 3; ++m) ax1[m] = *(const short8*)&x1b[m][nn][quad*8];
  const short8 am0 = *(const short8*)&m0b[nn][quad*8];

  const short* b000 = bt;
  const short* b001 = bt + 16384;
  const short* b110 = bt + 49152;
  const short* b111 = bt + 65536;
  const short* b012 = bt + 98304;
  const short* b102 = bt + 131072;

  float gs_p[4] = {}, gg_p[4] = {};
  float gv_p[3][4] = {};

  // T000: gs += sum_u m0[u] * (x0 @ Wg000[.,.,w])
  for (int u = wv; u < 16; u += 4) {
    const short* bp = b000 + (u*16 + nn)*64 + quad*8;
    const short8 b0 = *(const short8*)bp;
    const short8 b1 = *(const short8*)(bp + 32);
    f32x4 c = {0.f,0.f,0.f,0.f};
    c = __builtin_amdgcn_mfma_f32_16x16x32_bf16(ax0a, b0, c, 0,0,0);
    c = __builtin_amdgcn_mfma_f32_16x16x32_bf16(ax0c, b1, c, 0,0,0);
    const f32x4 t = *(const f32x4*)&m0t[u][eq];
#pragma unroll
    for (int r = 0; r < 4; ++r) gs_p[r] += t[r]*c[r];
  }
  // T110: gs += inv3 * sum_{u,m} m1[u,m] * (x1_m @ Wg110)   (inv3 in table)
#pragma unroll
  for (int m = 0; m < 3; ++m)
    for (int u = wv; u < 32; u += 4) {
      const short* bp = b110 + (u*16 + nn)*32 + quad*8;
      const short8 b0 = *(const short8*)bp;
      f32x4 c = {0.f,0.f,0.f,0.f};
      c = __builtin_amdgcn_mfma_f32_16x16x32_bf16(ax1[m], b0, c, 0,0,0);
      const f32x4 t = *(const f32x4*)&m1t[u][m][eq];
#pragma unroll
      for (int r = 0; r < 4; ++r) gs_p[r] += t[r]*c[r];
    }
  // T001: gg (w = wh*16+nn)
  for (int t2 = wv; t2 < 64; t2 += 4) {
    const int u = t2 >> 1;
    const short* bp = b001 + (u*32 + wh*16 + nn)*64 + quad*8;
    const short8 b0 = *(const short8*)bp;
    const short8 b1 = *(const short8*)(bp + 32);
    f32x4 c = {0.f,0.f,0.f,0.f};
    c = __builtin_amdgcn_mfma_f32_16x16x32_bf16(ax0a, b0, c, 0,0,0);
    c = __builtin_amdgcn_mfma_f32_16x16x32_bf16(ax0c, b1, c, 0,0,0);
    const f32x4 t = *(const f32x4*)&m0t[u][eq];
#pragma unroll
    for (int r = 0; r < 4; ++r) gg_p[r] += t[r]*c[r];
  }
  // T111: gg
#pragma unroll
  for (int m = 0; m < 3; ++m)
    for (int t2 = wv; t2 < 64; t2 += 4) {
      const int u = t2 >> 1;
      const short* bp = b111 + (u*32 + wh*16 + nn)*32 + quad*8;
      const short8 b0 = *(const short8*)bp;
      f32x4 c = {0.f,0.f,0.f,0.f};
      c = __builtin_amdgcn_mfma_f32_16x16x32_bf16(ax1[m], b0, c, 0,0,0);
      const f32x4 t = *(const f32x4*)&m1t[u][m][eq];
#pragma unroll
      for (int r = 0; r < 4; ++r) gg_p[r] += t[r]*c[r];
    }
  // T012: gv[w,m] += sum_v x1[v,m] * (m0 @ Wg012)[v*32+w]
  for (int t2 = wv; t2 < 64; t2 += 4) {
    const int v = t2 >> 1;
    const short* bp = b012 + (v*32 + wh*16 + nn)*32 + quad*8;
    const short8 b0 = *(const short8*)bp;
    f32x4 c = {0.f,0.f,0.f,0.f};
    c = __builtin_amdgcn_mfma_f32_16x16x32_bf16(am0, b0, c, 0,0,0);
#pragma unroll
    for (int m = 0; m < 3; ++m) {
      const f32x4 t = *(const f32x4*)&x1t[v][m][eq];
#pragma unroll
      for (int r = 0; r < 4; ++r) gv_p[m][r] += t[r]*c[r];
    }
  }
  // T102: gv[w,m] += sum_u m1[u,m] * (x0 @ Wg102)[u*32+w]
  for (int t2 = wv; t2 < 64; t2 += 4) {
    const int u = t2 >> 1;
    const short* bp = b102 + (u*32 + wh*16 + nn)*64 + quad*8;
    const short8 b0 = *(const short8*)bp;
    const short8 b1 = *(const short8*)(bp + 32);
    f32x4 c = {0.f,0.f,0.f,0.f};
    c = __builtin_amdgcn_mfma_f32_16x16x32_bf16(ax0a, b0, c, 0,0,0);
    c = __builtin_amdgcn_mfma_f32_16x16x32_bf16(ax0c, b1, c, 0,0,0);
#pragma unroll
    for (int m = 0; m < 3; ++m) {
      const f32x4 t = *(const f32x4*)&m1t[u][m][eq];
#pragma unroll
      for (int r = 0; r < 4; ++r) gv_p[m][r] += t[r]*c[r];
    }
  }

  // cross-wave combine
#pragma unroll
  for (int r = 0; r < 4; ++r) {
    atomicAdd(&gs_s[eq + r][nn], gs_p[r]);
    atomicAdd(&gg_s[eq + r][wh*16 + nn], gg_p[r]);
#pragma unroll
    for (int m = 0; m < 3; ++m)
      atomicAdd(&gv_s[eq + r][(wh*16 + nn)*3 + m], gv_p[m][r]);
  }
  __syncthreads();

  for (int i = tid; i < 16*112; i += 256) {
    int n = i / 112, f = i - n*112;
    float o;
    if (f < 16) {
      o = cst_sig / (1.f + expf(-PW_G01f * gs_s[n][f]));
    } else {
      int j = f - 16; int w = j/3;
      float gate = cst_tanh * tanhf(PW_G01f * gg_s[n][w]);
      o = gate * (PW_G2f * INV_SQRT3f) * gv_s[n][j];
    }
    xg[(n0+n)*112 + f] = o;
  }
}

// ---------------- K4: masked canonical pooling ----------------
__global__ __launch_bounds__(256) void k4_pool(const float* __restrict__ xg,
                                               const int* __restrict__ z,
                                               const int* __restrict__ canonical,
                                               float* __restrict__ sums,
                                               float* __restrict__ cnt) {
  int idx = blockIdx.x * 256 + threadIdx.x;
  int n = idx / 112, slot = idx - n*112;
  if (z[n] > 1) {
    int c = canonical[n];
    atomicAdd(&sums[c*112 + slot], xg[idx]);
    if (slot == 0) atomicAdd(&cnt[c], 1.f);
  }
}

// ---------------- K5: quadratic head -> th ----------------
__global__ __launch_bounds__(256) void k5_thead(const float* __restrict__ sums,
                                                const float* __restrict__ cnt,
                                                const float* __restrict__ Wa,
                                                const float* __restrict__ Wb,
                                                const float* __restrict__ Wc,
                                                const float* __restrict__ Wd,
                                                float* __restrict__ th) {
  __shared__ float xh_s[8][112];
  __shared__ float cm_s[8][1024];
  const int tid = threadIdx.x;
  const int n0 = blockIdx.x * 8;
  for (int i = tid; i < 8*112; i += 256) {
    int n = i / 112, j = i - n*112;
    float cv = fmaxf(cnt[n0+n], 1.f);
    xh_s[n][j] = sums[(n0+n)*112 + j] / cv;
  }
  __syncthreads();
  for (int i = tid; i < 8192; i += 256) {
    int n = i >> 10, uv = i & 1023, u = uv >> 5, v = uv & 31;
    const float* hh = xh_s[n] + 16;
    cm_s[n][uv] = hh[u*3]*hh[v*3] + hh[u*3+1]*hh[v*3+1] + hh[u*3+2]*hh[v*3+2];
  }
  __syncthreads();
  if (tid < 128) {
    int n = tid >> 4, k = tid & 15;
    float sA = 0.f;
    for (int v = 0; v < 16; ++v) sA += Wa[k*16+v]*xh_s[n][v];
    float wd = 0.f;
    const float* cp = cm_s[n];
#pragma unroll 4
    for (int uv = 0; uv < 1024; ++uv) wd += cp[uv]*Wd[uv*16 + k];
    th[(n0+n)*112 + k] = PW_H0f*(xh_s[n][k]*sA + INV_SQRT3f*wd);
  }
  {
    int n = tid >> 5, j = tid & 31;
    float wb = 0.f, wc = 0.f;
    for (int u = 0; u < 16; ++u) wb += Wb[u*32+j]*xh_s[n][u];
    for (int v = 0; v < 16; ++v) wc += Wc[j*16+v]*xh_s[n][v];
    float cb = PW_H1f * INV_SQRT3f * (wb + wc);
    const float* hh = xh_s[n] + 16;
    float* o = th + (n0+n)*112 + 16 + j*3;
    o[0] = cb*hh[j*3]; o[1] = cb*hh[j*3+1]; o[2] = cb*hh[j*3+2];
  }
}

// ---------------- K6: select + output linear ----------------
__global__ __launch_bounds__(256) void k6_out(const float* __restrict__ xg,
                                              const float* __restrict__ th,
                                              const int* __restrict__ z,
                                              const int* __restrict__ canonical,
                                              const float* __restrict__ WL0,
                                              const float* __restrict__ WL1,
                                              float* __restrict__ out) {
  int idx = blockIdx.x * 256 + threadIdx.x;
  int n = idx / 112, j = idx - n*112;
  const float* yr = (z[n] > 1) ? (th + canonical[n]*112) : (xg + n*112);
  float o = 0.f;
  if (j < 16) {
    for (int v = 0; v < 16; ++v) o += yr[v]*WL0[v*16 + j];
    o *= 0.25f;
  } else {
    int jj = j - 16, w = jj / 3, m = jj - w*3;
    for (int u = 0; u < 32; ++u) o += yr[16 + u*3 + m]*WL1[u*32 + w];
    o *= RSQRT32f;
  }
  out[idx] = o;
}

// ---------------- host: replicate numpy's trapz normalization constants ----
namespace {
struct Csts {
  float silu, sig, tanh_;
  Csts() {
    const int NPT = 200001;
    const double a = -12.0, b = 12.0;
    const double dx = (b - a) / (NPT - 1);
    double s1 = 0.0, s2 = 0.0, s3 = 0.0;
    for (int i = 0; i < NPT; ++i) {
      double xv = a + dx*i;
      double pdf = std::exp(-0.5*xv*xv) / std::sqrt(2.0*M_PI);
      double sg = 1.0 / (1.0 + std::exp(-xv));
      double f1 = xv*sg, f2 = sg, f3 = std::tanh(xv);
      double wg = (i == 0 || i == NPT-1) ? 0.5 : 1.0;
      s1 += wg*f1*f1*pdf; s2 += wg*f2*f2*pdf; s3 += wg*f3*f3*pdf;
    }
    silu  = (float)(1.0/std::sqrt(s1*dx));
    sig   = (float)(1.0/std::sqrt(s2*dx));
    tanh_ = (float)(1.0/std::sqrt(s3*dx));
  }
};
}  // namespace

extern "C" void kernel_launch(void* const* d_in, const int* in_sizes, int n_in,
                              void* d_out, int out_size, void* d_ws, size_t ws_size,
                              hipStream_t stream) {
  const float* x     = (const float*)d_in[0];
  const float* ea    = (const float*)d_in[1];
  const float* W1    = (const float*)d_in[2];
  const float* W2    = (const float*)d_in[3];
  const float* Wg000 = (const float*)d_in[4];
  const float* Wg110 = (const float*)d_in[5];
  const float* Wg001 = (const float*)d_in[6];
  const float* Wg111 = (const float*)d_in[7];
  const float* Wg012 = (const float*)d_in[8];
  const float* Wg102 = (const float*)d_in[9];
  const float* Wa    = (const float*)d_in[10];
  const float* Wb    = (const float*)d_in[11];
  const float* Wc    = (const float*)d_in[12];
  const float* Wd    = (const float*)d_in[13];
  const float* WL0   = (const float*)d_in[14];
  const float* WL1   = (const float*)d_in[15];
  const int* ei      = (const int*)d_in[16];
  const int* z       = (const int*)d_in[17];
  const int* canonical = (const int*)d_in[18];
  float* out = (float*)d_out;

  float* ws   = (float*)d_ws;          // 5,522,000 floats = 22.1 MB
  short* hbf  = (short*)ws;            // 3,072,000 bf16
  short* w2t  = (short*)(ws + 1536000);//   589,824 bf16
  short* bt   = (short*)(ws + 1831000);//   196,608 bf16 gate B-tables
  float* nm   = ws + 1930000;          //   896,000
  float* xg   = ws + 2826000;          //   896,000
  float* sums = ws + 3722000;          //   896,000
  float* cnt  = ws + 4618000;          //     8,000 (contiguous after sums)
  float* th   = ws + 4626000;          //   896,000

  static const Csts C;                 // host-only; safe under graph capture

  hipMemsetAsync(nm, 0, 896000*sizeof(float), stream);
  hipMemsetAsync(sums, 0, (896000+8000)*sizeof(float), stream);

  k1_h<<<12000, 256, 0, stream>>>(ea, W1, hbf, C.silu);
  k_w2t<<<2304, 256, 0, stream>>>(W2, w2t);
  k_wgt<<<768, 256, 0, stream>>>(Wg000, Wg110, Wg001, Wg111, Wg012, Wg102, bt);
  k2_edge_msg<<<750, 256, 0, stream>>>(x, ea, w2t, hbf, ei, nm);
  k3_gate<<<500, 256, 0, stream>>>(x, nm, bt, xg, C.sig, C.tanh_);
  k4_pool<<<3500, 256, 0, stream>>>(xg, z, canonical, sums, cnt);
  k5_thead<<<1000, 256, 0, stream>>>(sums, cnt, Wa, Wb, Wc, Wd, th);
  k6_out<<<3500, 256, 0, stream>>>(xg, th, z, canonical, WL0, WL1, out);
}